// Round 8
// baseline (976.724 us; speedup 1.0000x reference)
//
#include <hip/hip_runtime.h>
#include <math.h>

typedef __attribute__((ext_vector_type(8))) short s8v;    // 8 x bf16
typedef __attribute__((ext_vector_type(4))) short s4v;    // 4 x bf16
typedef __attribute__((ext_vector_type(4))) float f4v;    // 4 x f32
typedef __attribute__((ext_vector_type(16))) float f16v;  // 16 x f32 (32x32 acc)

static __device__ __forceinline__ unsigned short f2bf(float f) {
    union { float f; unsigned int u; } v; v.f = f;
    unsigned int r = v.u + 0x7fffu + ((v.u >> 16) & 1u);   // RNE
    return (unsigned short)(r >> 16);
}

// ---------- weight conversion: Wh[1],Wh[2] and Wout to bf16 ----------
__global__ void conv_bf16(const float* __restrict__ Wh, const float* __restrict__ Wout,
                          unsigned short* __restrict__ whbf, unsigned short* __restrict__ woutbf) {
    int i = blockIdx.x * 256 + threadIdx.x;
    if (i < 524288) {
        whbf[i] = f2bf(Wh[262144 + i]);            // layers 1,2 contiguous
    } else if (i < 524288 + 32768) {
        int j = i - 524288;
        woutbf[j] = f2bf(Wout[j]);
    }
}

// ---------- G0 = Wh0 @ W_in (512x64) fp32, + transposed bf16 copy ----------
__global__ void g0_kernel(const float* __restrict__ Wh0, const float* __restrict__ Win,
                          float* __restrict__ G0, unsigned short* __restrict__ G0tb) {
    int i = blockIdx.x;      // 0..511
    int j = threadIdx.x;     // 0..63
    float acc = 0.f;
    for (int k = 0; k < 512; ++k)
        acc = fmaf(Wh0[i * 512 + k], Win[k * 64 + j], acc);
    G0[i * 64 + j] = acc;
    G0tb[j * 512 + i] = f2bf(acc);
}

// ======== fp32 GEMM 128x64 tile (R4-validated), branch-fused over blockIdx.z ========
// mode bits: 1=+bias  2=relu  4=write C  8=write mask(u8)  16=mul by maskMul(u8)
__global__ __launch_bounds__(256) void gemm_nt(
    const float* __restrict__ X0, const float* __restrict__ X1, int ldx,
    const float* __restrict__ W, int ldw,
    const float* __restrict__ bias,
    float* __restrict__ C0, float* __restrict__ C1, int ldc,
    unsigned char* __restrict__ mo0, unsigned char* __restrict__ mo1,
    const unsigned char* __restrict__ mm0, const unsigned char* __restrict__ mm1,
    int K, int N, int mode)
{
    const int z = blockIdx.z;
    const float* __restrict__ X = z ? X1 : X0;
    float* __restrict__ C = z ? C1 : C0;
    unsigned char* __restrict__ maskOut = z ? mo1 : mo0;
    const unsigned char* __restrict__ maskMul = z ? mm1 : mm0;

    __shared__ float Xs[32][132];
    __shared__ float Ws[32][68];
    const int tid = threadIdx.x;
    const int m0 = blockIdx.x * 128;
    const int n0 = blockIdx.y * 64;
    const int tx = tid & 15, ty = tid >> 4;
    float acc[8][4] = {};

    float4 xr[4], wr[2];

    #define LOADCHUNK(k0)                                                        \
        {                                                                        \
            _Pragma("unroll")                                                    \
            for (int r = 0; r < 4; ++r) {                                        \
                int idx = tid + r * 256;                                         \
                int row = idx >> 3, kq = (idx & 7) * 4;                          \
                xr[r] = *(const float4*)(X + (size_t)(m0 + row) * ldx + (k0) + kq); \
            }                                                                    \
            _Pragma("unroll")                                                    \
            for (int r = 0; r < 2; ++r) {                                        \
                int idx = tid + r * 256;                                         \
                int row = idx >> 3, kq = (idx & 7) * 4;                          \
                wr[r] = *(const float4*)(W + (size_t)(n0 + row) * ldw + (k0) + kq); \
            }                                                                    \
        }
    #define STASH()                                                              \
        {                                                                        \
            _Pragma("unroll")                                                    \
            for (int r = 0; r < 4; ++r) {                                        \
                int idx = tid + r * 256;                                         \
                int row = idx >> 3, kq = (idx & 7) * 4;                          \
                Xs[kq + 0][row] = xr[r].x; Xs[kq + 1][row] = xr[r].y;            \
                Xs[kq + 2][row] = xr[r].z; Xs[kq + 3][row] = xr[r].w;            \
            }                                                                    \
            _Pragma("unroll")                                                    \
            for (int r = 0; r < 2; ++r) {                                        \
                int idx = tid + r * 256;                                         \
                int row = idx >> 3, kq = (idx & 7) * 4;                          \
                Ws[kq + 0][row] = wr[r].x; Ws[kq + 1][row] = wr[r].y;            \
                Ws[kq + 2][row] = wr[r].z; Ws[kq + 3][row] = wr[r].w;            \
            }                                                                    \
        }

    LOADCHUNK(0);
    STASH();
    __syncthreads();

    for (int k0 = 0; k0 < K; k0 += 32) {
        bool last = (k0 + 32 >= K);
        if (!last) LOADCHUNK(k0 + 32);
        #pragma unroll
        for (int kk = 0; kk < 32; ++kk) {
            float4 a0 = *(const float4*)&Xs[kk][ty * 4];
            float4 a1 = *(const float4*)&Xs[kk][64 + ty * 4];
            float4 b0 = *(const float4*)&Ws[kk][tx * 4];
            float av[8] = {a0.x, a0.y, a0.z, a0.w, a1.x, a1.y, a1.z, a1.w};
            float bv[4] = {b0.x, b0.y, b0.z, b0.w};
            #pragma unroll
            for (int i = 0; i < 8; ++i)
                #pragma unroll
                for (int j = 0; j < 4; ++j)
                    acc[i][j] = fmaf(av[i], bv[j], acc[i][j]);
        }
        __syncthreads();
        if (!last) {
            STASH();
            __syncthreads();
        }
    }

    float4 bb = {0, 0, 0, 0};
    if (mode & 1) bb = *(const float4*)(bias + n0 + tx * 4);
    const int c0 = n0 + tx * 4;
    #pragma unroll
    for (int i = 0; i < 8; ++i) {
        int r = m0 + ((i < 4) ? (ty * 4 + i) : (64 + ty * 4 + (i - 4)));
        float v[4];
        #pragma unroll
        for (int j = 0; j < 4; ++j) {
            v[j] = acc[i][j];
            if (mode & 1) v[j] += ((const float*)&bb)[j];
        }
        if (mode & 8) {
            uchar4 mo;
            mo.x = v[0] > 0.0f; mo.y = v[1] > 0.0f; mo.z = v[2] > 0.0f; mo.w = v[3] > 0.0f;
            *(uchar4*)&maskOut[(size_t)r * N + c0] = mo;
        }
        if (mode & 16) {
            uchar4 mm = *(const uchar4*)&maskMul[(size_t)r * N + c0];
            v[0] *= mm.x; v[1] *= mm.y; v[2] *= mm.z; v[3] *= mm.w;
        }
        if (mode & 2) {
            #pragma unroll
            for (int j = 0; j < 4; ++j) v[j] = fmaxf(v[j], 0.0f);
        }
        if (mode & 4) {
            float4 st = {v[0], v[1], v[2], v[3]};
            *(float4*)(C + (size_t)r * ldc + c0) = st;
        }
    }
}

// ---------- zng: Jacobian chain, 2 elems/block, stages on 32x32x16 MFMA ----------
// Rt layout: plain [n][k] with pad-520 stride (R2-validated). Phase A and the
// final 16x16 stage are the R2-validated forms; only the two big stages use
// 32x32x16 (C/D map: col=lane&31, row=(reg&3)+8*(reg>>2)+4*(lane>>5), m74/m101).
__global__ __launch_bounds__(512, 2) void zng_kernel(
    const unsigned short* __restrict__ whbf,   // [2][512][512] bf16 (layers 1,2)
    const unsigned short* __restrict__ woutbf, // [64][512] bf16
    const unsigned short* __restrict__ G0tb,   // [64][512] bf16 (G0 transposed)
    const unsigned char* __restrict__ mz1,
    const unsigned char* __restrict__ mz2,
    const unsigned char* __restrict__ mz3,
    float* __restrict__ out)                   // (4096,192), writes cols 128..191
{
    __shared__ __align__(16) unsigned short Rt[2][64 * 520];
    __shared__ unsigned char m2s[2][512];
    __shared__ unsigned char m3s[2][512];

    const int b0  = blockIdx.x * 2;
    const int tid = threadIdx.x;

    for (int i = tid; i < 1024; i += 512) {
        int bb = i >> 9, k = i & 511;
        m2s[bb][k] = mz2[(size_t)(b0 + bb) * 512 + k];
        m3s[bb][k] = mz3[(size_t)(b0 + bb) * 512 + k];
    }
    // Phase A (R2-validated): Rt[bb][n][k] = bf16(G0t[n][k]) * D1_bb[k]
    #pragma unroll 4
    for (int i = 0; i < 16; ++i) {
        int c = i * 512 + tid;             // 0..8191
        int bb = c >> 12, rem = c & 4095;
        int n = rem >> 6, k = (rem & 63) * 8;
        s8v g = *(const s8v*)(G0tb + n * 512 + k);
        const unsigned char* mm = mz1 + (size_t)(b0 + bb) * 512 + k;
        unsigned int mlo = *(const unsigned int*)(mm);
        unsigned int mhi = *(const unsigned int*)(mm + 4);
        s8v r;
        #pragma unroll
        for (int j = 0; j < 4; ++j) r[j] = ((mlo >> (8 * j)) & 1) ? g[j] : (short)0;
        #pragma unroll
        for (int j = 0; j < 4; ++j) r[4 + j] = ((mhi >> (8 * j)) & 1) ? g[4 + j] : (short)0;
        *(s8v*)(&Rt[bb][n * 520 + k]) = r;
    }
    __syncthreads();

    const int lane = tid & 63, wave = tid >> 6;
    const int ln5 = lane & 31;              // 32x32 free-index lane
    const int hh  = lane >> 5;              // k-half selector
    const int h8  = hh * 8;
    const int q = lane >> 4, ln = lane & 15; // 16x16 indices (final stage)

    // stages: Out_b = Wh[s+1] @ R_b ; R_b <- (D[s+2] (.) Out_b)^T   [32x32x16]
    for (int s = 0; s < 2; ++s) {
        const unsigned short* A = whbf + (size_t)s * 262144;
        f16v acc[2][2][2];                  // [bb][mt][nt], 16 f32 each
        #pragma unroll
        for (int bb = 0; bb < 2; ++bb)
            #pragma unroll
            for (int mt = 0; mt < 2; ++mt)
                #pragma unroll
                for (int nt = 0; nt < 2; ++nt)
                    acc[bb][mt][nt] = (f16v)(0.0f);

        const unsigned short* Ar0 = A + (size_t)(wave * 64 + ln5) * 512;
        const unsigned short* Ar1 = A + (size_t)(wave * 64 + 32 + ln5) * 512;
        s8v af[2], afn[2];
        af[0] = *(const s8v*)(Ar0 + h8);
        af[1] = *(const s8v*)(Ar1 + h8);

        #pragma unroll 2
        for (int ks = 0; ks < 32; ++ks) {
            int kn = ((ks + 1) & 31) * 16 + h8;       // wraps; redundant last load
            afn[0] = *(const s8v*)(Ar0 + kn);
            afn[1] = *(const s8v*)(Ar1 + kn);

            int kB = ks * 16 + h8;
            s8v bfr[2][2];
            #pragma unroll
            for (int bb = 0; bb < 2; ++bb)
                #pragma unroll
                for (int nt = 0; nt < 2; ++nt)
                    bfr[bb][nt] = *(const s8v*)(&Rt[bb][(nt * 32 + ln5) * 520 + kB]);

            #pragma unroll
            for (int mt = 0; mt < 2; ++mt)
                #pragma unroll
                for (int nt = 0; nt < 2; ++nt) {
                    acc[0][mt][nt] = __builtin_amdgcn_mfma_f32_32x32x16_bf16(af[mt], bfr[0][nt], acc[0][mt][nt], 0, 0, 0);
                    acc[1][mt][nt] = __builtin_amdgcn_mfma_f32_32x32x16_bf16(af[mt], bfr[1][nt], acc[1][mt][nt], 0, 0, 0);
                }
            af[0] = afn[0];
            af[1] = afn[1];
        }
        __syncthreads();   // all reads of old Rt done

        const unsigned char (*msk)[512] = (s == 0) ? m2s : m3s;
        #pragma unroll
        for (int bb = 0; bb < 2; ++bb)
            #pragma unroll
            for (int mt = 0; mt < 2; ++mt) {
                int base = wave * 64 + mt * 32;
                #pragma unroll
                for (int g = 0; g < 4; ++g) {
                    int mrow = base + 8 * g + 4 * hh;      // rows mrow..mrow+3
                    uchar4 mv = *(const uchar4*)&msk[bb][mrow];
                    unsigned char mb[4] = {mv.x, mv.y, mv.z, mv.w};
                    #pragma unroll
                    for (int nt = 0; nt < 2; ++nt) {
                        int n = nt * 32 + ln5;
                        s4v pk;
                        #pragma unroll
                        for (int r = 0; r < 4; ++r) {
                            float v = mb[r] ? acc[bb][mt][nt][4 * g + r] : 0.0f;
                            pk[r] = (short)f2bf(v);
                        }
                        *(s4v*)(&Rt[bb][n * 520 + mrow]) = pk;
                    }
                }
            }
        __syncthreads();
    }

    // final: g_b = Wout @ R3_b (64x64); zng[m] = ||g_b[m,:]||  (R2-validated, 16x16)
    {
        const int bb = wave >> 2, w4 = wave & 3;
        f4v acc3[4];
        #pragma unroll
        for (int nt = 0; nt < 4; ++nt) acc3[nt] = (f4v)(0.0f);
        for (int ks = 0; ks < 16; ++ks) {
            int kA = ks * 32 + q * 8;
            s8v af2 = *(const s8v*)(woutbf + (size_t)(w4 * 16 + ln) * 512 + kA);
            #pragma unroll
            for (int nt = 0; nt < 4; ++nt) {
                s8v bfr2 = *(const s8v*)(&Rt[bb][(nt * 16 + ln) * 520 + kA]);
                acc3[nt] = __builtin_amdgcn_mfma_f32_16x16x32_bf16(af2, bfr2, acc3[nt], 0, 0, 0);
            }
        }
        float ss[4];
        #pragma unroll
        for (int r = 0; r < 4; ++r) {
            float s2 = 0.f;
            #pragma unroll
            for (int nt = 0; nt < 4; ++nt) { float v = acc3[nt][r]; s2 = fmaf(v, v, s2); }
            ss[r] = s2;
        }
        #pragma unroll
        for (int off = 1; off < 16; off <<= 1)
            #pragma unroll
            for (int r = 0; r < 4; ++r)
                ss[r] += __shfl_xor(ss[r], off, 64);
        if (ln == 0) {
            #pragma unroll
            for (int r = 0; r < 4; ++r)
                out[(size_t)(b0 + bb) * 192 + 128 + w4 * 16 + q * 4 + r] = sqrtf(ss[r]);
        }
    }
}

// ---------- host ----------
extern "C" void kernel_launch(void* const* d_in, const int* in_sizes, int n_in,
                              void* d_out, int out_size, void* d_ws, size_t ws_size,
                              hipStream_t stream) {
    const float* x    = (const float*)d_in[0];
    const float* Win  = (const float*)d_in[1];
    const float* bin  = (const float*)d_in[2];
    const float* Wh   = (const float*)d_in[3];
    const float* bh   = (const float*)d_in[4];
    const float* Wout = (const float*)d_in[5];
    const float* bout = (const float*)d_in[6];
    float* out = (float*)d_out;

    char* ws = (char*)d_ws;
    float*          G0     = (float*)(ws);                         // 131072 B
    unsigned short* G0tb   = (unsigned short*)(ws + 131072);       // 65536 B
    unsigned short* whbf   = (unsigned short*)(ws + 196608);       // 1048576 B
    unsigned short* woutbf = (unsigned short*)(ws + 1245184);      // 65536 B
    unsigned char*  masks  = (unsigned char*)(ws + 1310720);       // 6 * 2 MB
    unsigned char* mt1 = masks + 0 * 2097152;
    unsigned char* mt2 = masks + 1 * 2097152;
    unsigned char* mt3 = masks + 2 * 2097152;
    unsigned char* mz1 = masks + 3 * 2097152;
    unsigned char* mz2 = masks + 4 * 2097152;
    unsigned char* mz3 = masks + 5 * 2097152;
    float* bufs = (float*)(ws + 1310720 + 12582912);               // 4 x 8 MB
    float* tA = bufs + 0 * 2097152;
    float* tB = bufs + 1 * 2097152;
    float* zA = bufs + 2 * 2097152;
    float* zB = bufs + 3 * 2097152;

    const float* Wh0 = Wh;
    const float* Wh1 = Wh + 262144;
    const float* Wh2 = Wh + 524288;
    const float* bh0 = bh, *bh1 = bh + 512, *bh2 = bh + 1024;

    conv_bf16<<<dim3(2176), dim3(256), 0, stream>>>(Wh, Wout, whbf, woutbf);
    g0_kernel<<<dim3(512), dim3(64), 0, stream>>>(Wh0, Win, G0, G0tb);

    // fused 2-branch GEMM launcher (Z=2) and single-branch (Z=1)
    auto gemm2 = [&](const float* X0, const float* X1, int ldx,
                     const float* W, int ldw, const float* bias,
                     float* C0, float* C1, int ldc,
                     unsigned char* mo0, unsigned char* mo1,
                     const unsigned char* mm0, const unsigned char* mm1,
                     int K, int N, int mode) {
        dim3 g(4096 / 128, N / 64, 2);
        gemm_nt<<<g, dim3(256), 0, stream>>>(X0, X1, ldx, W, ldw, bias, C0, C1, ldc,
                                             mo0, mo1, mm0, mm1, K, N, mode);
    };
    auto gemm1 = [&](const float* X, int ldx, const float* W, int ldw, const float* bias,
                     float* C, int ldc, unsigned char* mo, const unsigned char* mm,
                     int K, int N, int mode) {
        dim3 g(4096 / 128, N / 64, 1);
        gemm_nt<<<g, dim3(256), 0, stream>>>(X, 0, ldx, W, ldw, bias, C, 0, ldc,
                                             mo, 0, mm, 0, K, N, mode);
    };

    // ---- fused forward + delta chain (t: x[:,0:64] ; z: x[:,128:192]) ----
    gemm2(x, x + 128, 192, Win, 64, bin, tA, zA, 512, 0, 0, 0, 0, 64, 512, 1 | 4);          // h0
    gemm2(tA, zA, 512, Wh0, 512, bh0,    tB, zB, 512, 0, 0, 0, 0, 512, 512, 1 | 2 | 4);     // h1
    gemm2(tB, zB, 512, Wh0, 512, bh0,    0, 0, 0, mt1, mz1, 0, 0, 512, 512, 1 | 8);         // delta1
    gemm2(tB, zB, 512, Wh1, 512, bh1,    tA, zA, 512, 0, 0, 0, 0, 512, 512, 1 | 2 | 4);     // h2
    gemm2(tA, zA, 512, Wh1, 512, bh1,    0, 0, 0, mt2, mz2, 0, 0, 512, 512, 1 | 8);         // delta2
    gemm2(tA, zA, 512, Wh2, 512, bh2,    tB, zB, 512, 0, 0, 0, 0, 512, 512, 1 | 2 | 4);     // h3
    gemm2(tB, zB, 512, Wh2, 512, bh2,    0, 0, 0, mt3, mz3, 0, 0, 512, 512, 1 | 8);         // delta3

    // ---- zng (z-branch Jacobian row norms) ----
    zng_kernel<<<dim3(2048), dim3(512), 0, stream>>>(whbf, woutbf, G0tb, mz1, mz2, mz3, out);

    // ---- h_out (t-branch forward output) ----
    gemm1(tB, 512, Wout, 512, bout, out, 192, 0, 0, 512, 64, 1 | 4);                        // cols 0..63

    // ---- h_dot chain: V = D (.) (W v), contracted with xtdot up-front ----
    gemm1(x + 64, 192, G0, 64, 0, tA, 512, 0, mt1, 64, 512, 4 | 16);                        // V1
    gemm1(tA, 512, Wh1, 512, 0, zA, 512, 0, mt2, 512, 512, 4 | 16);                         // V2
    gemm1(zA, 512, Wh2, 512, 0, zB, 512, 0, mt3, 512, 512, 4 | 16);                         // V3
    gemm1(zB, 512, Wout, 512, 0, out + 64, 192, 0, 0, 512, 64, 4);                          // h_dot
}